// Round 3
// baseline (773.289 us; speedup 1.0000x reference)
//
#include <hip/hip_runtime.h>
#include <cstddef>

// CRF log-likelihood: B=128, L=1024, T=128.
// R8 vs R7 (261us bench / 183us rocprof): R7's 512-step fw/bw split scaled
// perfectly but kept the 858 cyc/step critical path: 4-wave barrier +
// cross-wave LDS exchange + 2 shuffle-combine stages. R8 removes ALL of it:
//   * ONE wave per chain (256 blocks x 64 threads, 1 per CU). Lane l owns
//     states 2l,2l+1; full k-sum in-thread -> no combine shuffles, and the
//     per-step alpha exchange is wave-internal ds_write -> lgkmcnt(0) ->
//     broadcast ds_read. No s_barrier anywhere in the recurrence.
//   * packed FP32: k-pairs from each b128 broadcast read feed v_pk_fma_f32
//     via <2 x float> __builtin_elementwise_fma -> 128 pk-FMA = 256 cyc
//     issue (vs 512 scalar). E-fragment lives in 256 VGPRs (reg budget is
//     free at 1 wave/SIMD).
//   * rescale every 8 steps is an exact power-of-2 from the lagged max's
//     exponent field (butterfly issued at i==0 mod 8, consumed at i+1,
//     latency hidden): zero transcendentals on the chain.
// Estimated ~380-450 cyc/step vs 858.

typedef float v2f __attribute__((ext_vector_type(2)));
typedef float v4f __attribute__((ext_vector_type(4)));

namespace {
constexpr int kB = 128, kL = 1024, kT = 128;
constexpr int kC = 16;   // rows per emission chunk
}

__device__ __forceinline__ v4f exp4v(v4f v) {
    return v4f{__expf(v.x), __expf(v.y), __expf(v.z), __expf(v.w)};
}

// full-k matvec for this lane's two states: out = (sum_k P[k]*E[k][s0],
//                                                  sum_k P[k]*E[k][s1])
__device__ __forceinline__ v2f matvec(const float* __restrict__ Pv,
                                      const v2f (&ek0)[64], const v2f (&ek1)[64])
{
    const v4f* __restrict__ p4 = (const v4f*)Pv;
    v2f a[4], b[4];
    #pragma unroll
    for (int i = 0; i < 4; ++i) { a[i] = 0.f; b[i] = 0.f; }
    #pragma unroll
    for (int t = 0; t < 32; ++t) {
        const v4f pv = p4[t];                       // broadcast b128: k = 4t..4t+3
        const v2f lo = __builtin_shufflevector(pv, pv, 0, 1);
        const v2f hi = __builtin_shufflevector(pv, pv, 2, 3);
        a[t & 3] = __builtin_elementwise_fma(lo, ek0[2 * t],     a[t & 3]);
        a[t & 3] = __builtin_elementwise_fma(hi, ek0[2 * t + 1], a[t & 3]);
        b[t & 3] = __builtin_elementwise_fma(lo, ek1[2 * t],     b[t & 3]);
        b[t & 3] = __builtin_elementwise_fma(hi, ek1[2 * t + 1], b[t & 3]);
    }
    const v2f ra = (a[0] + a[1]) + (a[2] + a[3]);
    const v2f rb = (b[0] + b[1]) + (b[2] + b[3]);
    v2f m;
    m.x = ra.x + ra.y;
    m.y = rb.x + rb.y;
    return m;
}

// ns steps; absolute step i = 1 + 16c + s -> phase (1+s)&7 (chunks 16-aligned).
// Rescale cadence identical to R5-R7 (apply lagged max at i==1 mod 8,
// refresh sample at i==0 mod 8).
__device__ __forceinline__ void run_steps(
    const float* __restrict__ emx, int emstride, int ns, int l,
    const v2f (&ek0)[64], const v2f (&ek1)[64],
    float (*P)[kT], float& C, float& wmax, int& cur)
{
    #pragma unroll 1
    for (int s = 0; s < ns; ++s) {
        const v2f em2 = *(const v2f*)(emx + s * emstride + 2 * l);
        v2f pm = matvec(P[cur], ek0, ek1);
        pm *= em2;
        const int phase = (s + 1) & 7;
        if (phase == 1) {                     // apply lagged normalizer (exact 2^-E)
            const int E = ((__float_as_int(wmax) >> 23) & 255) - 127;
            const float sc = __int_as_float((127 - E) << 23);
            C += (float)E * 0.6931471805599453f;
            pm *= sc;
        }
        const int nxt = cur ^ 1;
        *(v2f*)&P[nxt][2 * l] = pm;
        // single-wave exchange: drain LDS queue so all lanes' writes are
        // visible to next step's broadcast reads. No s_barrier.
        asm volatile("s_waitcnt lgkmcnt(0)" ::: "memory");
        if (phase == 0) {                     // refresh sample (consumed next step;
            float w = fmaxf(pm.x, pm.y);      //  butterfly latency hides under it)
            #pragma unroll
            for (int off = 1; off < 64; off <<= 1)
                w = fmaxf(w, __shfl_xor(w, off));
            wmax = w;
        }
        cur = nxt;
    }
}

__global__ __launch_bounds__(64, 1)
void crf_half(const float* __restrict__ logits,    // [B, L, T]
              const int* __restrict__ tags,         // [B, L]
              const float* __restrict__ trans,      // [T, T]
              const float* __restrict__ start_t,    // [T]
              const float* __restrict__ end_t,      // [T]
              float* __restrict__ ws)               // av[B][T], bg[B][T], cf[B], cb[B], num[B]
{
    const int b   = blockIdx.x & (kB - 1);
    const int dir = blockIdx.x >> 7;   // 0 = forward (steps 1..511 + bridge), 1 = backward (1022..512)
    const int l   = threadIdx.x;       // lane 0..63; states 2l, 2l+1

    __shared__ __align__(16) float P[2][kT];         // scaled vector, dbuf (1KB)
    __shared__ __align__(16) float em[2][kC * kT];   // exp(emission) chunks (16KB)

    const float* mylog = logits + (size_t)b * kL * kT;

    // ---------------- numerator (gold-path score), backward blocks ----------------
    float num = 0.f;
    if (dir == 1) {
        const int* mytags = tags + b * kL;
        float ns = 0.f;
        for (int p = l; p < kL; p += 64) {
            const int tg = mytags[p];
            ns += mylog[(size_t)p * kT + tg];
            if (p < kL - 1) ns += trans[tg * kT + mytags[p + 1]];
        }
        if (l == 0) ns += start_t[mytags[0]] + end_t[mytags[kL - 1]];
        #pragma unroll
        for (int off = 1; off < 64; off <<= 1) ns += __shfl_xor(ns, off);
        num = ns;
    }

    // ---------------- E fragments: 128 v2f in registers ----------------
    // k-pair kk -> ek0[kk] = (E[2kk][s0], E[2kk+1][s0]), ek1 for s1.
    // forward: E[k][j] = exp(trans[k][j]); backward: E[k][j] = exp(trans[j][k]).
    v2f ek0[64], ek1[64];
    if (dir == 0) {
        #pragma unroll
        for (int t = 0; t < 64; ++t) {
            const v2f te = *(const v2f*)(trans + (2 * t) * kT + 2 * l);
            const v2f to = *(const v2f*)(trans + (2 * t + 1) * kT + 2 * l);
            ek0[t] = v2f{__expf(te.x), __expf(to.x)};
            ek1[t] = v2f{__expf(te.y), __expf(to.y)};
        }
    } else {
        #pragma unroll
        for (int t = 0; t < 32; ++t) {
            const v4f r0 = *(const v4f*)(trans + (2 * l) * kT + 4 * t);
            const v4f r1 = *(const v4f*)(trans + (2 * l + 1) * kT + 4 * t);
            ek0[2 * t]     = v2f{__expf(r0.x), __expf(r0.y)};
            ek0[2 * t + 1] = v2f{__expf(r0.z), __expf(r0.w)};
            ek1[2 * t]     = v2f{__expf(r1.x), __expf(r1.y)};
            ek1[2 * t + 1] = v2f{__expf(r1.z), __expf(r1.w)};
        }
    }

    // ---------------- init vector + initial normalizer sample ----------------
    float C = 0.f, wmax;
    {
        float v0, v1;
        if (dir == 0) {
            v0 = start_t[2 * l]     + mylog[2 * l];
            v1 = start_t[2 * l + 1] + mylog[2 * l + 1];
        } else {
            const size_t r = (size_t)(kL - 1) * kT;
            v0 = end_t[2 * l]     + mylog[r + 2 * l];
            v1 = end_t[2 * l + 1] + mylog[r + 2 * l + 1];
        }
        v2f p;
        p.x = __expf(v0);
        p.y = __expf(v1);
        *(v2f*)&P[0][2 * l] = p;
        asm volatile("s_waitcnt lgkmcnt(0)" ::: "memory");
        float w = fmaxf(p.x, p.y);
        #pragma unroll
        for (int off = 1; off < 64; off <<= 1) w = fmaxf(w, __shfl_xor(w, off));
        wmax = w;
    }

    // ---------------- emission chunk staging (pre-exp'd, dbuf) ----------------
    // fwd: chunks ascend from row 1 (rows 1..512 staged, 1..511 used);
    // bwd: chunk c holds ascending rows 1007-16c..1022-16c, consumed in
    // reverse via emstride=-kT from offset 15*kT (rows 1022 down to 512).
    const int base0 = (dir == 0) ? kT : 1007 * kT;
    const int cstep = (dir == 0) ? 16 * kT : -16 * kT;

    #pragma unroll
    for (int i = 0; i < 8; ++i) {
        const v4f r = *(const v4f*)(mylog + base0 + 256 * i + 4 * l);
        *(v4f*)(&em[0][256 * i + 4 * l]) = exp4v(r);
    }
    v4f g[8];
    #pragma unroll
    for (int i = 0; i < 8; ++i)
        g[i] = *(const v4f*)(mylog + base0 + cstep + 256 * i + 4 * l);
    asm volatile("s_waitcnt lgkmcnt(0)" ::: "memory");

    // ---------------- main recurrence: 511 steps (31x16 + 15) ----------------
    int cur = 0;
    const int emoff    = (dir == 0) ? 0 : 15 * kT;
    const int emstride = (dir == 0) ? kT : -kT;

    #pragma unroll 1
    for (int c = 0; c < 31; ++c) {
        float* dst = em[(c + 1) & 1];       // consumed >=16 steps after write
        #pragma unroll
        for (int i = 0; i < 8; ++i)
            *(v4f*)(dst + 256 * i + 4 * l) = exp4v(g[i]);
        if (c <= 29) {                      // preload chunk c+2 (rows in-bounds:
            const int base2 = base0 + (c + 2) * cstep;   // fwd max 497, bwd min 511)
            #pragma unroll
            for (int i = 0; i < 8; ++i)
                g[i] = *(const v4f*)(mylog + base2 + 256 * i + 4 * l);
        }
        run_steps(em[c & 1] + emoff, emstride, kC, l, ek0, ek1, P, C, wmax, cur);
    }
    run_steps(em[1] + emoff, emstride, kC - 1, l, ek0, ek1, P, C, wmax, cur);

    // ---------------- epilogue ----------------
    float* ws_av = ws;                 // [kB][kT]
    float* ws_bg = ws + kB * kT;       // [kB][kT]
    float* ws_sc = ws + 2 * kB * kT;   // cf[kB], cb[kB], num[kB]

    if (dir == 0) {
        // bridge: av = E^T alpha_511 (transition 511->512, no emission/rescale)
        const v2f m = matvec(P[cur], ek0, ek1);
        *(v2f*)(ws_av + b * kT + 2 * l) = m;
        if (l == 0) ws_sc[b] = C;
    } else {
        const v2f pv = *(const v2f*)&P[cur][2 * l];
        *(v2f*)(ws_bg + b * kT + 2 * l) = pv;
        if (l == 0) {
            ws_sc[kB + b]     = C;
            ws_sc[2 * kB + b] = num;
        }
    }
}

// Z_b = exp(cf+cb) * <av, bg>; out += sum_b (num_b - log Z_b)
__global__ void crf_combine(const float* __restrict__ ws, float* __restrict__ out)
{
    const int b = blockIdx.x;
    const int t = threadIdx.x;   // 0..63
    const float2 av = *(const float2*)(ws + b * kT + 2 * t);
    const float2 bg = *(const float2*)(ws + kB * kT + b * kT + 2 * t);
    float fp = av.x * bg.x + av.y * bg.y;
    #pragma unroll
    for (int off = 1; off < 64; off <<= 1) fp += __shfl_xor(fp, off);
    if (t == 0) {
        const float* sc = ws + 2 * kB * kT;
        const float logZ = sc[b] + sc[kB + b] + __logf(fp);
        atomicAdd(out, sc[2 * kB + b] - logZ);
    }
}

extern "C" void kernel_launch(void* const* d_in, const int* in_sizes, int n_in,
                              void* d_out, int out_size, void* d_ws, size_t ws_size,
                              hipStream_t stream) {
    const float* logits  = (const float*)d_in[0];
    const int*   tags    = (const int*)d_in[1];
    // d_in[2] = mask -- all true in this problem's setup, unused
    const float* trans   = (const float*)d_in[3];
    const float* start_t = (const float*)d_in[4];
    const float* end_t   = (const float*)d_in[5];
    float* out = (float*)d_out;
    float* ws  = (float*)d_ws;   // (2*128*128 + 3*128) floats = ~130 KB

    hipMemsetAsync(out, 0, sizeof(float), stream);
    crf_half<<<dim3(2 * kB), dim3(64), 0, stream>>>(logits, tags, trans, start_t, end_t, ws);
    crf_combine<<<dim3(kB), dim3(64), 0, stream>>>(ws, out);
}

// Round 4
// 311.600 us; speedup vs baseline: 2.4817x; 2.4817x over previous
//
#include <hip/hip_runtime.h>
#include <cstddef>

// CRF log-likelihood: B=128, L=1024, T=128.
// R9: revert to R7's proven 4-wave fw/bw split (183us rocprof), then attack
// the 858 cyc/step path without touching the sync structure. R8's 1-wave
// design (695us) proved per-lane E storage is the binding constraint: 256
// E floats/lane spilled to scratch (VGPR=164) and scratch loads ate the
// chain. R7's 64 E floats/thread is the right mapping; its VGPR_Count=64
// says the (256,2) launch bound register-starved even that.
//   * __launch_bounds__(256,1): VGPR cap 512, E + emission regs actually
//     fit. Grid is 256 blocks on 256 CUs -- nothing lost.
//   * packed fp32: E as 32 v2f (state-pair interleaved), v_pk_fma_f32 via
//     <2 x float> elementwise_fma -> 32 pk-FMA/step vs 64 scalar.
//   * emissions in REGISTERS: thread consumes only its own 2 floats/step;
//     16-step chunk = 16 v2f, double-buffered (g prefetched 1 chunk ahead,
//     exp'd at chunk boundary). Kills the per-step em ds_read, all staging
//     ds_writes, and 16KB of LDS.
// P exchange / shuffles / lagged normalizer / barrier: identical to R7.

typedef float v2f __attribute__((ext_vector_type(2)));
typedef float v4f __attribute__((ext_vector_type(4)));

namespace {
constexpr int kB   = 128;
constexpr int kL   = 1024;
constexpr int kT   = 128;
constexpr int kC   = 16;     // steps per emission chunk
constexpr int kSec = 36;     // padded P section stride (32 data + 4 pad)
}

__device__ __forceinline__ v2f expv2(v2f v) { return v2f{__expf(v.x), __expf(v.y)}; }

// NS steps; absolute step i = 1 + 16c + s -> phase (1+s)&7 (chunks 16-aligned).
// Cadence identical to R5-R7: apply lagged max at i==1 mod 8, refresh at 0.
template<int NS>
__device__ __forceinline__ void run_steps(
    const v2f (&emr)[kC],                     // this chunk's exp(emissions), regs
    int pr, int q, int wv, const v2f (&epk)[32],
    int widx, float (*P)[4 * kSec], float* lnm_s, float& C, int& cur)
{
    #pragma unroll
    for (int s = 0; s < NS; ++s) {
        const v4f* p4 = (const v4f*)(P[cur] + kSec * q);   // 144B-aligned bcast
        v2f a0{0.f, 0.f}, a1{0.f, 0.f}, a2{0.f, 0.f}, a3{0.f, 0.f};
        #pragma unroll
        for (int t = 0; t < 8; ++t) {
            const v4f pv = p4[t];             // broadcast b128: k = 4t..4t+3
            a0 = __builtin_elementwise_fma(v2f{pv.x, pv.x}, epk[4 * t + 0], a0);
            a1 = __builtin_elementwise_fma(v2f{pv.y, pv.y}, epk[4 * t + 1], a1);
            a2 = __builtin_elementwise_fma(v2f{pv.z, pv.z}, epk[4 * t + 2], a2);
            a3 = __builtin_elementwise_fma(v2f{pv.w, pv.w}, epk[4 * t + 3], a3);
        }
        v2f m = (a0 + a1) + (a2 + a3);
        m.x += __shfl_xor(m.x, 1);            // combine 4 k-quarters
        m.y += __shfl_xor(m.y, 1);
        m.x += __shfl_xor(m.x, 2);
        m.y += __shfl_xor(m.y, 2);

        v2f pm = m * emr[s];                  // emission from register
        const int phase = (1 + s) & 7;
        if (phase == 1) {                     // apply lagged normalizer
            const float lnm = *lnm_s;         // published before last barrier
            C += lnm;
            pm *= __expf(-lnm);
        }
        const int nxt = cur ^ 1;
        if (q == 0) *(v2f*)&P[nxt][widx] = pm;
        if (phase == 0 && wv == 0) {          // refresh normalizer sample
            float w = fmaxf(pm.x, pm.y);      // wave 0 holds states 0..31
            #pragma unroll
            for (int off = 4; off < 64; off <<= 1)
                w = fmaxf(w, __shfl_xor(w, off));
            if (threadIdx.x == 0) *lnm_s = (w > 0.f) ? __logf(w) : 0.f;
        }
        cur = nxt;
        __syncthreads();
    }
}

__global__ __launch_bounds__(256, 1)
void crf_half(const float* __restrict__ logits,    // [B, L, T]
              const int* __restrict__ tags,         // [B, L]
              const float* __restrict__ trans,      // [T, T]
              const float* __restrict__ start_t,    // [T]
              const float* __restrict__ end_t,      // [T]
              float* __restrict__ ws)               // av[B][T], bg[B][T], cf, cb, num
{
    const int b    = blockIdx.x & (kB - 1);
    const int dir  = blockIdx.x >> 7;  // 0 = fwd (steps 1..511 + bridge), 1 = bwd (1022..512)
    const int tid  = threadIdx.x;      // 0..255
    const int pr   = tid >> 2;         // state pair 0..63 -> states 2pr, 2pr+1
    const int q    = tid & 3;          // k-quarter
    const int lane = tid & 63;
    const int wv   = tid >> 6;         // 0..3

    __shared__ __align__(16) float P[2][4 * kSec];   // padded scaled vector, dbuf
    __shared__ float lnm_s;
    __shared__ float red[4];

    const float* mylog = logits + (size_t)b * kL * kT;

    // ---------------- numerator (gold-path score), backward blocks ----------------
    float num = 0.f;
    if (dir == 1) {
        const int* mytags = tags + b * kL;
        float ns = 0.f;
        for (int p = tid; p < kL; p += 256) {
            const int tg = mytags[p];
            ns += mylog[(size_t)p * kT + tg];
            if (p < kL - 1) ns += trans[tg * kT + mytags[p + 1]];
        }
        if (tid == 0) ns += start_t[mytags[0]] + end_t[mytags[kL - 1]];
        #pragma unroll
        for (int off = 1; off < 64; off <<= 1) ns += __shfl_xor(ns, off);
        if (lane == 0) red[wv] = ns;
    }
    __syncthreads();
    if (dir == 1 && tid == 0) num = (red[0] + red[1]) + (red[2] + red[3]);

    // ---------------- E fragment: 32 v2f in registers ----------------
    // epk[i] = (E[32q+i][2pr], E[32q+i][2pr+1]);
    // fwd E[k][j] = exp(trans[k][j])  (straight float2 load);
    // bwd E[k][j] = exp(trans[j][k])  (two row reads, interleave).
    v2f epk[32];
    if (dir == 0) {
        #pragma unroll
        for (int i = 0; i < 32; ++i)
            epk[i] = expv2(*(const v2f*)(trans + (32 * q + i) * kT + 2 * pr));
    } else {
        #pragma unroll
        for (int i = 0; i < 8; ++i) {
            const v4f r0 = *(const v4f*)(trans + (2 * pr)     * kT + 32 * q + 4 * i);
            const v4f r1 = *(const v4f*)(trans + (2 * pr + 1) * kT + 32 * q + 4 * i);
            epk[4 * i + 0] = v2f{__expf(r0.x), __expf(r1.x)};
            epk[4 * i + 1] = v2f{__expf(r0.y), __expf(r1.y)};
            epk[4 * i + 2] = v2f{__expf(r0.z), __expf(r1.z)};
            epk[4 * i + 3] = v2f{__expf(r0.w), __expf(r1.w)};
        }
    }

    const int widx = kSec * (pr >> 4) + ((2 * pr) & 31);   // slot for state 2pr

    // ---------------- init: vector + first normalizer sample ----------------
    {
        v2f v;
        if (dir == 0) {
            v.x = start_t[2 * pr]     + mylog[2 * pr];
            v.y = start_t[2 * pr + 1] + mylog[2 * pr + 1];
        } else {
            const size_t r = (size_t)(kL - 1) * kT;
            v.x = end_t[2 * pr]     + mylog[r + 2 * pr];
            v.y = end_t[2 * pr + 1] + mylog[r + 2 * pr + 1];
        }
        const v2f p0 = expv2(v);
        if (q == 0) *(v2f*)&P[0][widx] = p0;
        if (wv == 0) {
            float w = fmaxf(p0.x, p0.y);
            #pragma unroll
            for (int off = 4; off < 64; off <<= 1) w = fmaxf(w, __shfl_xor(w, off));
            if (tid == 0) lnm_s = __logf(w);
        }
    }

    // ---------------- emission registers: chunk c row s = rb + rs*(16c+s) ----------------
    const int rb = dir ? 1022 : 1;
    const int rs = dir ? -1 : 1;
    const float* embase = mylog + 2 * pr;

    v2f emr[kC], g[kC];
    #pragma unroll
    for (int s = 0; s < kC; ++s)
        emr[s] = *(const v2f*)(embase + (size_t)(rb + rs * s) * kT);
    #pragma unroll
    for (int s = 0; s < kC; ++s)
        g[s] = *(const v2f*)(embase + (size_t)(rb + rs * (kC + s)) * kT);
    #pragma unroll
    for (int s = 0; s < kC; ++s) emr[s] = expv2(emr[s]);
    __syncthreads();   // P[0] + lnm_s visible

    // ---------------- main recurrence: 511 steps (31x16 + 15) ----------------
    float C   = 0.f;
    int   cur = 0;

    #pragma unroll 1
    for (int c = 0; c < 31; ++c) {
        run_steps<kC>(emr, pr, q, wv, epk, widx, P, &lnm_s, C, cur);
        #pragma unroll
        for (int s = 0; s < kC; ++s) emr[s] = expv2(g[s]);   // chunk c+1 -> emr
        if (c <= 29) {                                       // prefetch chunk c+2
            const int base2 = rb + rs * kC * (c + 2);        // rows: fwd max 512, bwd min 511
            #pragma unroll
            for (int s = 0; s < kC; ++s)
                g[s] = *(const v2f*)(embase + (size_t)(base2 + rs * s) * kT);
        }
    }
    run_steps<kC - 1>(emr, pr, q, wv, epk, widx, P, &lnm_s, C, cur);   // steps 497..511

    // ---------------- epilogue ----------------
    float* ws_av = ws;                 // [kB][kT]
    float* ws_bg = ws + kB * kT;       // [kB][kT]
    float* ws_sc = ws + 2 * kB * kT;   // cf[kB], cb[kB], num[kB]

    if (dir == 0) {
        // bridge: av = E^T alpha_511 (transition 511->512, no emission/rescale)
        const v4f* p4 = (const v4f*)(P[cur] + kSec * q);
        v2f a0{0.f, 0.f}, a1{0.f, 0.f}, a2{0.f, 0.f}, a3{0.f, 0.f};
        #pragma unroll
        for (int t = 0; t < 8; ++t) {
            const v4f pv = p4[t];
            a0 = __builtin_elementwise_fma(v2f{pv.x, pv.x}, epk[4 * t + 0], a0);
            a1 = __builtin_elementwise_fma(v2f{pv.y, pv.y}, epk[4 * t + 1], a1);
            a2 = __builtin_elementwise_fma(v2f{pv.z, pv.z}, epk[4 * t + 2], a2);
            a3 = __builtin_elementwise_fma(v2f{pv.w, pv.w}, epk[4 * t + 3], a3);
        }
        v2f m = (a0 + a1) + (a2 + a3);
        m.x += __shfl_xor(m.x, 1);
        m.y += __shfl_xor(m.y, 1);
        m.x += __shfl_xor(m.x, 2);
        m.y += __shfl_xor(m.y, 2);
        if (q == 0) *(v2f*)(ws_av + b * kT + 2 * pr) = m;
        if (tid == 0) ws_sc[b] = C;
    } else {
        if (q == 0) {
            const v2f pv = *(const v2f*)&P[cur][widx];
            *(v2f*)(ws_bg + b * kT + 2 * pr) = pv;
        }
        if (tid == 0) {
            ws_sc[kB + b]     = C;
            ws_sc[2 * kB + b] = num;
        }
    }
}

// Z_b = exp(cf+cb) * <av, bg>; out += sum_b (num_b - log Z_b)
__global__ void crf_combine(const float* __restrict__ ws, float* __restrict__ out)
{
    const int b = blockIdx.x;
    const int t = threadIdx.x;   // 0..63
    const float2 av = *(const float2*)(ws + b * kT + 2 * t);
    const float2 bg = *(const float2*)(ws + kB * kT + b * kT + 2 * t);
    float fp = av.x * bg.x + av.y * bg.y;
    #pragma unroll
    for (int off = 1; off < 64; off <<= 1) fp += __shfl_xor(fp, off);
    if (t == 0) {
        const float* sc = ws + 2 * kB * kT;
        const float logZ = sc[b] + sc[kB + b] + __logf(fp);
        atomicAdd(out, sc[2 * kB + b] - logZ);
    }
}

extern "C" void kernel_launch(void* const* d_in, const int* in_sizes, int n_in,
                              void* d_out, int out_size, void* d_ws, size_t ws_size,
                              hipStream_t stream) {
    const float* logits  = (const float*)d_in[0];
    const int*   tags    = (const int*)d_in[1];
    // d_in[2] = mask -- all true in this problem's setup, unused
    const float* trans   = (const float*)d_in[3];
    const float* start_t = (const float*)d_in[4];
    const float* end_t   = (const float*)d_in[5];
    float* out = (float*)d_out;
    float* ws  = (float*)d_ws;   // (2*128*128 + 3*128) floats = ~130 KB

    hipMemsetAsync(out, 0, sizeof(float), stream);
    crf_half<<<dim3(2 * kB), dim3(256), 0, stream>>>(logits, tags, trans, start_t, end_t, ws);
    crf_combine<<<dim3(kB), dim3(64), 0, stream>>>(ws, out);
}

// Round 5
// 276.498 us; speedup vs baseline: 2.7967x; 1.1270x over previous
//
#include <hip/hip_runtime.h>
#include <cstddef>

// CRF log-likelihood: B=128, L=1024, T=128.
// R10 = R7 skeleton (183us rocprof, the proven anchor) + two zero-register
// critical-path cuts. R9 (240us) proved emission/prefetch arrays in VGPRs
// crowd out the matvec's read-pipelining regs (VGPR=92 < needed ~130 ->
// exposed LDS latency). So: emissions stay in LDS exactly as R7.
//   * DPP quad combine: tid = 4*pr + q puts the 4 k-quarter lanes in one
//     DPP quad; the two dependent __shfl_xor (ds_swizzle, ~70-140 cyc) become
//     v_add_f32 + quad_perm DPP (~8 cyc, no LDS pipe, no lgkmcnt).
//   * packed fp32 matvec: E as 32 v2f (state-pair interleaved),
//     v_pk_fma_f32 -> 32 pk-FMA/step vs 64 scalar (-64 cyc issue).
// Everything else (staging, cadence, normalizer, fw/bw split, epilogue,
// combine kernel) is byte-identical to R7.

typedef float v2f __attribute__((ext_vector_type(2)));
typedef float v4f __attribute__((ext_vector_type(4)));

namespace {
constexpr int kB   = 128;
constexpr int kL   = 1024;
constexpr int kT   = 128;
constexpr int kC   = 16;     // steps per emission chunk
constexpr int kSec = 36;     // padded P section stride (32 data + 4 pad)
}

__device__ __forceinline__ v4f exp4v(v4f v) {
    return v4f{__expf(v.x), __expf(v.y), __expf(v.z), __expf(v.w)};
}

// sum across the 4-lane DPP quad (lanes differing in bits 0-1 = k-quarter q).
// quad_perm[1,0,3,2] = 0xB1 (xor 1), quad_perm[2,3,0,1] = 0x4E (xor 2).
__device__ __forceinline__ float quad_sum(float x) {
    int xi = __float_as_int(x);
    x += __int_as_float(__builtin_amdgcn_update_dpp(0, xi, 0xB1, 0xF, 0xF, true));
    xi = __float_as_int(x);
    x += __int_as_float(__builtin_amdgcn_update_dpp(0, xi, 0x4E, 0xF, 0xF, true));
    return x;
}

// NS steps; absolute step i = 1 + 16c + s -> phase (1+s)&7 (chunks 16-aligned).
// Cadence identical to R5-R7: apply lagged max at i==1 mod 8, refresh at 0.
template<int NS>
__device__ __forceinline__ void run_steps(
    const float* __restrict__ emx, int emstride,
    int pr, int q, int wv, const v2f (&epk)[32],
    int widx, float (*P)[4 * kSec], float* lnm_s, float& C, int& cur)
{
    #pragma unroll
    for (int s = 0; s < NS; ++s) {
        const v4f* p4 = (const v4f*)(P[cur] + kSec * q);   // 144B-aligned bcast
        v2f a0{0.f, 0.f}, a1{0.f, 0.f}, a2{0.f, 0.f}, a3{0.f, 0.f};
        #pragma unroll
        for (int t = 0; t < 8; ++t) {
            const v4f pv = p4[t];             // broadcast b128: k = 32q+4t..+3
            a0 = __builtin_elementwise_fma(v2f{pv.x, pv.x}, epk[4 * t + 0], a0);
            a1 = __builtin_elementwise_fma(v2f{pv.y, pv.y}, epk[4 * t + 1], a1);
            a2 = __builtin_elementwise_fma(v2f{pv.z, pv.z}, epk[4 * t + 2], a2);
            a3 = __builtin_elementwise_fma(v2f{pv.w, pv.w}, epk[4 * t + 3], a3);
        }
        const v2f acc = (a0 + a1) + (a2 + a3);
        v2f m;
        m.x = quad_sum(acc.x);                // combine 4 k-quarters via DPP
        m.y = quad_sum(acc.y);

        // pre-exp'd emissions for states 2pr, 2pr+1 (4-way broadcast b64)
        const v2f ex = *(const v2f*)(emx + s * emstride + 2 * pr);
        v2f pm = m * ex;
        const int phase = (1 + s) & 7;
        if (phase == 1) {                     // apply lagged normalizer
            const float lnm = *lnm_s;         // published before last barrier
            C += lnm;
            pm *= __expf(-lnm);
        }
        const int nxt = cur ^ 1;
        if (q == 0) *(v2f*)&P[nxt][widx] = pm;
        if (phase == 0 && wv == 0) {          // refresh normalizer sample
            float w = fmaxf(pm.x, pm.y);      // wave 0 holds states 0..31
            #pragma unroll
            for (int off = 4; off < 64; off <<= 1)
                w = fmaxf(w, __shfl_xor(w, off));
            if (threadIdx.x == 0) *lnm_s = (w > 0.f) ? __logf(w) : 0.f;
        }
        cur = nxt;
        __syncthreads();
    }
}

__global__ __launch_bounds__(256, 2)
void crf_half(const float* __restrict__ logits,    // [B, L, T]
              const int* __restrict__ tags,         // [B, L]
              const float* __restrict__ trans,      // [T, T]
              const float* __restrict__ start_t,    // [T]
              const float* __restrict__ end_t,      // [T]
              float* __restrict__ ws)               // av[B][T], bg[B][T], cf, cb, num
{
    const int b    = blockIdx.x & (kB - 1);
    const int dir  = blockIdx.x >> 7;  // 0 = fwd (steps 1..511 + bridge), 1 = bwd (1022..512)
    const int tid  = threadIdx.x;      // 0..255
    const int pr   = tid >> 2;         // state pair 0..63 -> states 2pr, 2pr+1
    const int q    = tid & 3;          // k-quarter
    const int lane = tid & 63;
    const int wv   = tid >> 6;         // 0..3

    __shared__ __align__(16) float P[2][4 * kSec];   // padded scaled vector, dbuf
    __shared__ __align__(16) float em[2][kC * kT];   // exp(emission) chunks, 8KB
    __shared__ float lnm_s;
    __shared__ float red[4];

    const float* mylog = logits + (size_t)b * kL * kT;

    // ---------------- numerator (gold-path score), backward blocks ----------------
    float num = 0.f;
    if (dir == 1) {
        const int* mytags = tags + b * kL;
        float ns = 0.f;
        for (int p = tid; p < kL; p += 256) {
            const int tg = mytags[p];
            ns += mylog[(size_t)p * kT + tg];
            if (p < kL - 1) ns += trans[tg * kT + mytags[p + 1]];
        }
        if (tid == 0) ns += start_t[mytags[0]] + end_t[mytags[kL - 1]];
        #pragma unroll
        for (int off = 1; off < 64; off <<= 1) ns += __shfl_xor(ns, off);
        if (lane == 0) red[wv] = ns;
    }
    __syncthreads();
    if (dir == 1 && tid == 0) num = (red[0] + red[1]) + (red[2] + red[3]);

    // ---------------- E fragment: 32 v2f in registers ----------------
    // epk[i] = (E[32q+i][2pr], E[32q+i][2pr+1]);
    // fwd E[k][j] = exp(trans[k][j])  (straight float2 load);
    // bwd E[k][j] = exp(trans[j][k])  (two row reads, interleave).
    v2f epk[32];
    if (dir == 0) {
        #pragma unroll
        for (int i = 0; i < 32; ++i) {
            const v2f tv = *(const v2f*)(trans + (32 * q + i) * kT + 2 * pr);
            epk[i] = v2f{__expf(tv.x), __expf(tv.y)};
        }
    } else {
        #pragma unroll
        for (int i = 0; i < 8; ++i) {
            const v4f r0 = *(const v4f*)(trans + (2 * pr)     * kT + 32 * q + 4 * i);
            const v4f r1 = *(const v4f*)(trans + (2 * pr + 1) * kT + 32 * q + 4 * i);
            epk[4 * i + 0] = v2f{__expf(r0.x), __expf(r1.x)};
            epk[4 * i + 1] = v2f{__expf(r0.y), __expf(r1.y)};
            epk[4 * i + 2] = v2f{__expf(r0.z), __expf(r1.z)};
            epk[4 * i + 3] = v2f{__expf(r0.w), __expf(r1.w)};
        }
    }

    const int widx = kSec * (pr >> 4) + ((2 * pr) & 31);   // slot for state 2pr

    // ---------------- init: vector + first normalizer sample ----------------
    {
        v2f v;
        if (dir == 0) {
            v.x = start_t[2 * pr]     + mylog[2 * pr];
            v.y = start_t[2 * pr + 1] + mylog[2 * pr + 1];
        } else {
            const size_t r = (size_t)(kL - 1) * kT;
            v.x = end_t[2 * pr]     + mylog[r + 2 * pr];
            v.y = end_t[2 * pr + 1] + mylog[r + 2 * pr + 1];
        }
        const v2f p0 = v2f{__expf(v.x), __expf(v.y)};
        if (q == 0) *(v2f*)&P[0][widx] = p0;
        if (wv == 0) {
            float w = fmaxf(p0.x, p0.y);
            #pragma unroll
            for (int off = 4; off < 64; off <<= 1) w = fmaxf(w, __shfl_xor(w, off));
            if (tid == 0) lnm_s = __logf(w);
        }
    }

    // ---------------- emission chunk staging (pre-exp'd, dbuf) ----------------
    // fwd: chunks ascend from row 1; bwd: chunk c holds ascending rows
    // 1007-16c..1022-16c, consumed in reverse (emstride -kT from 15*kT).
    // Contiguous float4 layout: conflict-free ds_write, coalesced global.
    const int base0 = (dir == 0) ? kT : 1007 * kT;
    const int cstep = (dir == 0) ? 16 * kT : -16 * kT;

    *(v4f*)(&em[0][4 * tid])        = exp4v(*(const v4f*)(mylog + base0 + 4 * tid));
    *(v4f*)(&em[0][1024 + 4 * tid]) = exp4v(*(const v4f*)(mylog + base0 + 1024 + 4 * tid));
    v4f g0 = *(const v4f*)(mylog + base0 + cstep + 4 * tid);
    v4f g1 = *(const v4f*)(mylog + base0 + cstep + 1024 + 4 * tid);
    __syncthreads();

    // ---------------- main recurrence: 511 steps (31x16 + 15) ----------------
    float C   = 0.f;
    int   cur = 0;
    const int emoff    = (dir == 0) ? 0 : 15 * kT;
    const int emstride = (dir == 0) ? kT : -kT;

    #pragma unroll 1
    for (int c = 0; c < 31; ++c) {
        // publish chunk c+1 (buffer (c+1)&1: consumed >=16 barriers later)
        *(v4f*)(&em[(c + 1) & 1][4 * tid])        = exp4v(g0);
        *(v4f*)(&em[(c + 1) & 1][1024 + 4 * tid]) = exp4v(g1);
        if (c <= 29) {   // preload chunk c+2 (rows in-bounds: fwd max 497, bwd min 511)
            const int base2 = base0 + (c + 2) * cstep;
            g0 = *(const v4f*)(mylog + base2 + 4 * tid);
            g1 = *(const v4f*)(mylog + base2 + 1024 + 4 * tid);
        }
        run_steps<kC>(em[c & 1] + emoff, emstride, pr, q, wv, epk, widx, P, &lnm_s, C, cur);
    }
    // chunk 31: 15 steps, emissions already in em[1]
    run_steps<kC - 1>(em[1] + emoff, emstride, pr, q, wv, epk, widx, P, &lnm_s, C, cur);

    // ---------------- epilogue ----------------
    float* ws_av = ws;                 // [kB][kT]
    float* ws_bg = ws + kB * kT;       // [kB][kT]
    float* ws_sc = ws + 2 * kB * kT;   // cf[kB], cb[kB], num[kB]

    if (dir == 0) {
        // bridge: av = E^T alpha_511 (transition 511->512, no emission/rescale)
        const v4f* p4 = (const v4f*)(P[cur] + kSec * q);
        v2f a0{0.f, 0.f}, a1{0.f, 0.f}, a2{0.f, 0.f}, a3{0.f, 0.f};
        #pragma unroll
        for (int t = 0; t < 8; ++t) {
            const v4f pv = p4[t];
            a0 = __builtin_elementwise_fma(v2f{pv.x, pv.x}, epk[4 * t + 0], a0);
            a1 = __builtin_elementwise_fma(v2f{pv.y, pv.y}, epk[4 * t + 1], a1);
            a2 = __builtin_elementwise_fma(v2f{pv.z, pv.z}, epk[4 * t + 2], a2);
            a3 = __builtin_elementwise_fma(v2f{pv.w, pv.w}, epk[4 * t + 3], a3);
        }
        const v2f acc = (a0 + a1) + (a2 + a3);
        v2f m;
        m.x = quad_sum(acc.x);
        m.y = quad_sum(acc.y);
        if (q == 0) *(v2f*)(ws_av + b * kT + 2 * pr) = m;
        if (tid == 0) ws_sc[b] = C;
    } else {
        if (q == 0) {
            const v2f pv = *(const v2f*)&P[cur][widx];
            *(v2f*)(ws_bg + b * kT + 2 * pr) = pv;
        }
        if (tid == 0) {
            ws_sc[kB + b]     = C;
            ws_sc[2 * kB + b] = num;
        }
    }
}

// Z_b = exp(cf+cb) * <av, bg>; out += sum_b (num_b - log Z_b)
__global__ void crf_combine(const float* __restrict__ ws, float* __restrict__ out)
{
    const int b = blockIdx.x;
    const int t = threadIdx.x;   // 0..63
    const float2 av = *(const float2*)(ws + b * kT + 2 * t);
    const float2 bg = *(const float2*)(ws + kB * kT + b * kT + 2 * t);
    float fp = av.x * bg.x + av.y * bg.y;
    #pragma unroll
    for (int off = 1; off < 64; off <<= 1) fp += __shfl_xor(fp, off);
    if (t == 0) {
        const float* sc = ws + 2 * kB * kT;
        const float logZ = sc[b] + sc[kB + b] + __logf(fp);
        atomicAdd(out, sc[2 * kB + b] - logZ);
    }
}

extern "C" void kernel_launch(void* const* d_in, const int* in_sizes, int n_in,
                              void* d_out, int out_size, void* d_ws, size_t ws_size,
                              hipStream_t stream) {
    const float* logits  = (const float*)d_in[0];
    const int*   tags    = (const int*)d_in[1];
    // d_in[2] = mask -- all true in this problem's setup, unused
    const float* trans   = (const float*)d_in[3];
    const float* start_t = (const float*)d_in[4];
    const float* end_t   = (const float*)d_in[5];
    float* out = (float*)d_out;
    float* ws  = (float*)d_ws;   // (2*128*128 + 3*128) floats = ~130 KB

    hipMemsetAsync(out, 0, sizeof(float), stream);
    crf_half<<<dim3(2 * kB), dim3(256), 0, stream>>>(logits, tags, trans, start_t, end_t, ws);
    crf_combine<<<dim3(kB), dim3(64), 0, stream>>>(ws, out);
}

// Round 6
// 248.998 us; speedup vs baseline: 3.1056x; 1.1104x over previous
//
#include <hip/hip_runtime.h>
#include <cstddef>

// CRF log-likelihood: B=128, L=1024, T=128.
// R11 = R7 (183us rocprof anchor) + ONE change: the 4-lane k-quarter combine
// switches from two dependent __shfl_xor (ds_bpermute/ds_swizzle: LDS pipe,
// lgkmcnt waits, ~70-140 cyc/step) to DPP quad_perm adds (pure VALU, ~8 cyc).
// Lanes 4*pr+q put the 4 k-quarters in one DPP quad, so quad_perm[1,0,3,2]
// and quad_perm[2,3,0,1] implement xor1/xor2 exactly.
// Post-mortems driving this:
//   R8 (695us): >64 E floats/lane -> spill; single-wave dead.
//   R9 (240us): emission regs crowd out matvec pipelining regs; emissions
//               must stay in LDS.
//   R10 (219us): pk-FMA v2f splats broke the clean scalar 8-chain FMA
//               schedule -> keep R7's scalar e0/e1 form untouched.
// Everything else (staging, cadence, normalizer, fw/bw split, epilogue,
// combine kernel, launch bounds) is byte-identical to R7.

namespace {
constexpr int kB   = 128;
constexpr int kL   = 1024;
constexpr int kT   = 128;
constexpr int kC   = 16;     // steps per emission chunk
constexpr int kSec = 36;     // padded P section stride (32 data + 4 pad)
}

__device__ __forceinline__ float4 exp4(float4 v) {
    return make_float4(__expf(v.x), __expf(v.y), __expf(v.z), __expf(v.w));
}

// sum across the 4-lane DPP quad (lanes differing in bits 0-1 = k-quarter q).
// quad_perm[1,0,3,2] = 0xB1 (xor 1), quad_perm[2,3,0,1] = 0x4E (xor 2).
__device__ __forceinline__ float quad_sum(float x) {
    int xi = __float_as_int(x);
    x += __int_as_float(__builtin_amdgcn_update_dpp(0, xi, 0xB1, 0xF, 0xF, true));
    xi = __float_as_int(x);
    x += __int_as_float(__builtin_amdgcn_update_dpp(0, xi, 0x4E, 0xF, 0xF, true));
    return x;
}

// NS steps of the scaled recurrence. emx points at this chunk's first-step
// emission row; emstride = +kT (forward) or -kT (backward). Chunk starts are
// 16-step aligned so (1+s)&7 is the absolute-step phase.
template<int NS>
__device__ __forceinline__ void run_steps(
    const float* __restrict__ emx, int emstride,
    int pr, int q, int wv, const float (&e0)[32], const float (&e1)[32],
    int widx, float (*P)[4 * kSec], float* lnm_s, float& C, int& cur)
{
    #pragma unroll
    for (int s = 0; s < NS; ++s) {
        const float4* p4 = (const float4*)(P[cur] + kSec * q);   // 144B-aligned
        float a00 = 0.f, a01 = 0.f, a02 = 0.f, a03 = 0.f;
        float a10 = 0.f, a11 = 0.f, a12 = 0.f, a13 = 0.f;
        #pragma unroll
        for (int t = 0; t < 8; ++t) {
            const float4 pv = p4[t];              // broadcast, const offset
            a00 = fmaf(pv.x, e0[4 * t + 0], a00); // const reg indices
            a01 = fmaf(pv.y, e0[4 * t + 1], a01);
            a02 = fmaf(pv.z, e0[4 * t + 2], a02);
            a03 = fmaf(pv.w, e0[4 * t + 3], a03);
            a10 = fmaf(pv.x, e1[4 * t + 0], a10);
            a11 = fmaf(pv.y, e1[4 * t + 1], a11);
            a12 = fmaf(pv.z, e1[4 * t + 2], a12);
            a13 = fmaf(pv.w, e1[4 * t + 3], a13);
        }
        float m0 = (a00 + a01) + (a02 + a03);
        float m1 = (a10 + a11) + (a12 + a13);
        m0 = quad_sum(m0);                        // combine 4 k-quarters (DPP)
        m1 = quad_sum(m1);

        // pre-exp'd emissions for states 2pr, 2pr+1 (4-way broadcast b64)
        const float2 ex = *(const float2*)(emx + s * emstride + 2 * pr);
        float p0 = m0 * ex.x;
        float p1 = m1 * ex.y;
        if (((1 + s) & 7) == 1) {                 // apply lagged normalizer
            const float lnm = *lnm_s;             // published before last barrier
            C += lnm;
            const float sc = __expf(-lnm);
            p0 *= sc;
            p1 *= sc;
        }

        const int nxt = cur ^ 1;
        if (q == 0) *(float2*)(&P[nxt][widx]) = make_float2(p0, p1);
        if (((1 + s) & 7) == 0 && wv == 0) {      // refresh normalizer sample
            float w = fmaxf(p0, p1);              // wave 0 holds states 0..31
            #pragma unroll
            for (int off = 4; off < 64; off <<= 1)
                w = fmaxf(w, __shfl_xor(w, off));
            if (threadIdx.x == 0) *lnm_s = (w > 0.f) ? __logf(w) : 0.f;
        }
        cur = nxt;
        __syncthreads();
    }
}

__global__ __launch_bounds__(256, 2)
void crf_half(const float* __restrict__ logits,    // [B, L, T]
              const int* __restrict__ tags,         // [B, L]
              const float* __restrict__ trans,      // [T, T]
              const float* __restrict__ start_t,    // [T]
              const float* __restrict__ end_t,      // [T]
              float* __restrict__ ws)               // av[B][T], bg[B][T], cf[B], cb[B], num[B]
{
    const int b    = blockIdx.x & (kB - 1);
    const int dir  = blockIdx.x >> 7;  // 0 = forward (steps 1..511 + bridge), 1 = backward (1022..512)
    const int tid  = threadIdx.x;      // 0..255
    const int pr   = tid >> 2;         // state pair 0..63 -> states 2pr, 2pr+1
    const int q    = tid & 3;          // k-quarter
    const int lane = tid & 63;
    const int wv   = tid >> 6;         // 0..3

    __shared__ __align__(16) float P[2][4 * kSec];   // padded scaled vector, dbuf
    __shared__ __align__(16) float em[2][kC * kT];   // exp(emission) chunks, 8KB
    __shared__ float lnm_s;
    __shared__ float red[4];

    const float* mylog = logits + (size_t)b * kL * kT;

    // ---------------- numerator (gold-path score), backward blocks ----------------
    float num = 0.f;
    if (dir == 1) {
        const int* mytags = tags + b * kL;
        float ns = 0.f;
        for (int p = tid; p < kL; p += 256) {
            const int tg = mytags[p];
            ns += mylog[(size_t)p * kT + tg];
            if (p < kL - 1) ns += trans[tg * kT + mytags[p + 1]];
        }
        if (tid == 0) ns += start_t[mytags[0]] + end_t[mytags[kL - 1]];
        #pragma unroll
        for (int off = 1; off < 64; off <<= 1) ns += __shfl_xor(ns, off);
        if (lane == 0) red[wv] = ns;
    }
    __syncthreads();
    if (dir == 1 && tid == 0) num = (red[0] + red[1]) + (red[2] + red[3]);

    // ---------------- E fragments in registers ----------------
    // forward: e0[t] = exp(trans[32q+t][2pr])   (output state = column)
    // backward: e0[t] = exp(trans[2pr][32q+t])  (output state = row)
    float e0[32], e1[32];
    if (dir == 0) {
        #pragma unroll
        for (int t = 0; t < 32; ++t) {
            const float2 tv = *(const float2*)(trans + (32 * q + t) * kT + 2 * pr);
            e0[t] = __expf(tv.x);
            e1[t] = __expf(tv.y);
        }
    } else {
        #pragma unroll
        for (int t4 = 0; t4 < 8; ++t4) {
            const float4 r0 = *(const float4*)(trans + (2 * pr)     * kT + 32 * q + 4 * t4);
            const float4 r1 = *(const float4*)(trans + (2 * pr + 1) * kT + 32 * q + 4 * t4);
            e0[4 * t4 + 0] = __expf(r0.x);  e0[4 * t4 + 1] = __expf(r0.y);
            e0[4 * t4 + 2] = __expf(r0.z);  e0[4 * t4 + 3] = __expf(r0.w);
            e1[4 * t4 + 0] = __expf(r1.x);  e1[4 * t4 + 1] = __expf(r1.y);
            e1[4 * t4 + 2] = __expf(r1.z);  e1[4 * t4 + 3] = __expf(r1.w);
        }
    }

    const int widx = kSec * (pr >> 4) + ((2 * pr) & 31);   // slot for state 2pr

    // ---------------- init vector ----------------
    // forward:  alpha_0 = exp(start + emit_0)
    // backward: bg_1023 = exp(end + emit_1023)
    {
        float v0, v1;
        if (dir == 0) {
            v0 = start_t[2 * pr]     + mylog[2 * pr];
            v1 = start_t[2 * pr + 1] + mylog[2 * pr + 1];
        } else {
            const size_t r = (size_t)(kL - 1) * kT;
            v0 = end_t[2 * pr]     + mylog[r + 2 * pr];
            v1 = end_t[2 * pr + 1] + mylog[r + 2 * pr + 1];
        }
        const float p0 = __expf(v0);
        const float p1 = __expf(v1);
        if (q == 0) *(float2*)(&P[0][widx]) = make_float2(p0, p1);
        if (wv == 0) {
            float w = fmaxf(p0, p1);
            #pragma unroll
            for (int off = 4; off < 64; off <<= 1) w = fmaxf(w, __shfl_xor(w, off));
            if (tid == 0) lnm_s = __logf(w);
        }
    }

    // ---------------- emission chunk staging ----------------
    // fwd: chunks ascend from row 1; bwd: chunk c holds ascending rows
    // 1007-16c..1022-16c, consumed in reverse via emstride=-kT from 15*kT.
    // Contiguous float4 layout: conflict-free ds_write_b128, coalesced global.
    const int base0 = (dir == 0) ? kT : 1007 * kT;
    const int cstep = (dir == 0) ? 16 * kT : -16 * kT;

    *(float4*)(&em[0][4 * tid])        = exp4(*(const float4*)(mylog + base0 + 4 * tid));
    *(float4*)(&em[0][1024 + 4 * tid]) = exp4(*(const float4*)(mylog + base0 + 1024 + 4 * tid));
    float4 g0 = *(const float4*)(mylog + base0 + cstep + 4 * tid);
    float4 g1 = *(const float4*)(mylog + base0 + cstep + 1024 + 4 * tid);
    __syncthreads();

    // ---------------- main recurrence: 511 steps (31 full chunks + 15) ----------------
    float C   = 0.f;
    int   cur = 0;
    const int emoff    = (dir == 0) ? 0 : 15 * kT;   // first-step row within chunk
    const int emstride = (dir == 0) ? kT : -kT;

    #pragma unroll 1
    for (int c = 0; c < 31; ++c) {
        // publish chunk c+1 (buffer (c+1)&1: consumed >=16 barriers later)
        *(float4*)(&em[(c + 1) & 1][4 * tid])        = exp4(g0);
        *(float4*)(&em[(c + 1) & 1][1024 + 4 * tid]) = exp4(g1);
        if (c <= 29) {   // preload chunk c+2 (rows in-bounds: fwd max 497, bwd min 511)
            const int base2 = base0 + (c + 2) * cstep;
            g0 = *(const float4*)(mylog + base2 + 4 * tid);
            g1 = *(const float4*)(mylog + base2 + 1024 + 4 * tid);
        }
        run_steps<kC>(em[c & 1] + emoff, emstride, pr, q, wv, e0, e1, widx, P, &lnm_s, C, cur);
    }
    // chunk 31: 15 steps (fwd rows 497..511 / bwd rows 526..512), already in em[1]
    run_steps<kC - 1>(em[1] + emoff, emstride, pr, q, wv, e0, e1, widx, P, &lnm_s, C, cur);

    // ---------------- epilogue ----------------
    float* ws_av = ws;                 // [kB][kT] scaled av = E^T alpha_511
    float* ws_bg = ws + kB * kT;       // [kB][kT] scaled bg_512
    float* ws_sc = ws + 2 * kB * kT;   // cf[kB], cb[kB], num[kB]

    if (dir == 0) {
        // bridge matvec: av[j] = sum_k alpha_511[k] * exp(trans[k][j])
        // (transition 511->512; no emission, no rescale)
        const float4* p4 = (const float4*)(P[cur] + kSec * q);
        float a00 = 0.f, a01 = 0.f, a02 = 0.f, a03 = 0.f;
        float a10 = 0.f, a11 = 0.f, a12 = 0.f, a13 = 0.f;
        #pragma unroll
        for (int t = 0; t < 8; ++t) {
            const float4 pv = p4[t];
            a00 = fmaf(pv.x, e0[4 * t + 0], a00);
            a01 = fmaf(pv.y, e0[4 * t + 1], a01);
            a02 = fmaf(pv.z, e0[4 * t + 2], a02);
            a03 = fmaf(pv.w, e0[4 * t + 3], a03);
            a10 = fmaf(pv.x, e1[4 * t + 0], a10);
            a11 = fmaf(pv.y, e1[4 * t + 1], a11);
            a12 = fmaf(pv.z, e1[4 * t + 2], a12);
            a13 = fmaf(pv.w, e1[4 * t + 3], a13);
        }
        float m0 = (a00 + a01) + (a02 + a03);
        float m1 = (a10 + a11) + (a12 + a13);
        m0 = quad_sum(m0);
        m1 = quad_sum(m1);
        if (q == 0) {
            ws_av[b * kT + 2 * pr]     = m0;
            ws_av[b * kT + 2 * pr + 1] = m1;
        }
        if (tid == 0) ws_sc[b] = C;
    } else {
        if (q == 0) {
            const float2 pv = *(const float2*)(&P[cur][widx]);
            ws_bg[b * kT + 2 * pr]     = pv.x;
            ws_bg[b * kT + 2 * pr + 1] = pv.y;
        }
        if (tid == 0) {
            ws_sc[kB + b]     = C;
            ws_sc[2 * kB + b] = num;
        }
    }
}

// Z_b = exp(cf+cb) * <av, bg>; out += sum_b (num_b - log Z_b)
__global__ void crf_combine(const float* __restrict__ ws, float* __restrict__ out)
{
    const int b = blockIdx.x;
    const int t = threadIdx.x;   // 0..63
    const float2 av = *(const float2*)(ws + b * kT + 2 * t);
    const float2 bg = *(const float2*)(ws + kB * kT + b * kT + 2 * t);
    float fp = av.x * bg.x + av.y * bg.y;
    #pragma unroll
    for (int off = 1; off < 64; off <<= 1) fp += __shfl_xor(fp, off);
    if (t == 0) {
        const float* sc = ws + 2 * kB * kT;
        const float logZ = sc[b] + sc[kB + b] + __logf(fp);
        atomicAdd(out, sc[2 * kB + b] - logZ);
    }
}

extern "C" void kernel_launch(void* const* d_in, const int* in_sizes, int n_in,
                              void* d_out, int out_size, void* d_ws, size_t ws_size,
                              hipStream_t stream) {
    const float* logits  = (const float*)d_in[0];
    const int*   tags    = (const int*)d_in[1];
    // d_in[2] = mask -- all true in this problem's setup, unused
    const float* trans   = (const float*)d_in[3];
    const float* start_t = (const float*)d_in[4];
    const float* end_t   = (const float*)d_in[5];
    float* out = (float*)d_out;
    float* ws  = (float*)d_ws;   // (2*128*128 + 3*128) floats = ~130 KB

    hipMemsetAsync(out, 0, sizeof(float), stream);
    crf_half<<<dim3(2 * kB), dim3(256), 0, stream>>>(logits, tags, trans, start_t, end_t, ws);
    crf_combine<<<dim3(kB), dim3(64), 0, stream>>>(ws, out);
}

// Round 7
// 240.570 us; speedup vs baseline: 3.2144x; 1.0350x over previous
//
#include <hip/hip_runtime.h>
#include <cstddef>

// CRF log-likelihood: B=128, L=1024, T=128.
// R12 = R11 (171us rocprof) + two stall cuts, skeleton untouched:
//   1. lgkm-only barrier in the recurrence: __syncthreads() lowers to
//      s_waitcnt vmcnt(0) lgkmcnt(0) + s_barrier, so the first barrier after
//      each chunk's 2 global prefetch loads drained HBM (~700-900 cyc / 16
//      steps ~= 50 cyc/step). Raw "s_waitcnt lgkmcnt(0)" + s_barrier (HK
//      8-phase pattern) keeps prefetch in flight; compiler still inserts the
//      vmcnt wait where g0/g1 are consumed.
//   2. DPP normalizer reduce: the every-8-step wave-0 max was 4 dependent
//      __shfl_xor (ds_swizzle, LDS pipe, ~140-240 cyc all waves wait out).
//      Now 4 DPP max stages (row_ror:4, row_ror:8, bcast15, bcast31), pure
//      VALU ~25 cyc; wave-0 lane 63 publishes. Any published value is exact
//      (C += lnm compensates), it only needs to track magnitude.
// Ladder: R7 183us (fw/bw split) -> R11 171us (DPP quad combine).
// Failed branches: R8 695us (1-wave, E spill), R9 240us (emission regs evict
// pipelining regs), R10 219us (pk-FMA splats break scalar FMA schedule).

namespace {
constexpr int kB   = 128;
constexpr int kL   = 1024;
constexpr int kT   = 128;
constexpr int kC   = 16;     // steps per emission chunk
constexpr int kSec = 36;     // padded P section stride (32 data + 4 pad)
}

__device__ __forceinline__ float4 exp4(float4 v) {
    return make_float4(__expf(v.x), __expf(v.y), __expf(v.z), __expf(v.w));
}

// barrier that drains only the LDS/shfl queue -- global loads stay in flight
__device__ __forceinline__ void lgkm_barrier() {
    asm volatile("s_waitcnt lgkmcnt(0)" ::: "memory");
    __builtin_amdgcn_s_barrier();
}

// sum across the 4-lane DPP quad (lanes differing in bits 0-1 = k-quarter q).
// quad_perm[1,0,3,2] = 0xB1 (xor 1), quad_perm[2,3,0,1] = 0x4E (xor 2).
__device__ __forceinline__ float quad_sum(float x) {
    int xi = __float_as_int(x);
    x += __int_as_float(__builtin_amdgcn_update_dpp(0, xi, 0xB1, 0xF, 0xF, true));
    xi = __float_as_int(x);
    x += __int_as_float(__builtin_amdgcn_update_dpp(0, xi, 0x4E, 0xF, 0xF, true));
    return x;
}

// wave-wide max via DPP, valid when values repeat with period 4 (post-quad).
// row_ror:4 (0x124) + row_ror:8 (0x128) give each lane its 16-row max;
// bcast15 (0x142, rows 1,3) then bcast31 (0x143, rows 2,3) fold rows so
// lanes 48..63 hold the full-wave max. Pure VALU, no LDS pipe.
__device__ __forceinline__ float wave_max_dpp(float x) {
    int xi = __float_as_int(x);
    x = fmaxf(x, __int_as_float(__builtin_amdgcn_update_dpp(0, xi, 0x124, 0xF, 0xF, true)));
    xi = __float_as_int(x);
    x = fmaxf(x, __int_as_float(__builtin_amdgcn_update_dpp(0, xi, 0x128, 0xF, 0xF, true)));
    xi = __float_as_int(x);
    x = fmaxf(x, __int_as_float(__builtin_amdgcn_update_dpp(xi, xi, 0x142, 0xa, 0xF, false)));
    xi = __float_as_int(x);
    x = fmaxf(x, __int_as_float(__builtin_amdgcn_update_dpp(xi, xi, 0x143, 0xc, 0xF, false)));
    return x;   // lanes 48..63 valid
}

// NS steps of the scaled recurrence. emx points at this chunk's first-step
// emission row; emstride = +kT (forward) or -kT (backward). Chunk starts are
// 16-step aligned so (1+s)&7 is the absolute-step phase.
template<int NS>
__device__ __forceinline__ void run_steps(
    const float* __restrict__ emx, int emstride,
    int pr, int q, int wv, const float (&e0)[32], const float (&e1)[32],
    int widx, float (*P)[4 * kSec], float* lnm_s, float& C, int& cur)
{
    #pragma unroll
    for (int s = 0; s < NS; ++s) {
        const float4* p4 = (const float4*)(P[cur] + kSec * q);   // 144B-aligned
        float a00 = 0.f, a01 = 0.f, a02 = 0.f, a03 = 0.f;
        float a10 = 0.f, a11 = 0.f, a12 = 0.f, a13 = 0.f;
        #pragma unroll
        for (int t = 0; t < 8; ++t) {
            const float4 pv = p4[t];              // broadcast, const offset
            a00 = fmaf(pv.x, e0[4 * t + 0], a00); // const reg indices
            a01 = fmaf(pv.y, e0[4 * t + 1], a01);
            a02 = fmaf(pv.z, e0[4 * t + 2], a02);
            a03 = fmaf(pv.w, e0[4 * t + 3], a03);
            a10 = fmaf(pv.x, e1[4 * t + 0], a10);
            a11 = fmaf(pv.y, e1[4 * t + 1], a11);
            a12 = fmaf(pv.z, e1[4 * t + 2], a12);
            a13 = fmaf(pv.w, e1[4 * t + 3], a13);
        }
        float m0 = (a00 + a01) + (a02 + a03);
        float m1 = (a10 + a11) + (a12 + a13);
        m0 = quad_sum(m0);                        // combine 4 k-quarters (DPP)
        m1 = quad_sum(m1);

        // pre-exp'd emissions for states 2pr, 2pr+1 (4-way broadcast b64)
        const float2 ex = *(const float2*)(emx + s * emstride + 2 * pr);
        float p0 = m0 * ex.x;
        float p1 = m1 * ex.y;
        if (((1 + s) & 7) == 1) {                 // apply lagged normalizer
            const float lnm = *lnm_s;             // published before last barrier
            C += lnm;
            const float sc = __expf(-lnm);
            p0 *= sc;
            p1 *= sc;
        }

        const int nxt = cur ^ 1;
        if (q == 0) *(float2*)(&P[nxt][widx]) = make_float2(p0, p1);
        if (((1 + s) & 7) == 0 && wv == 0) {      // refresh normalizer sample
            const float w = wave_max_dpp(fmaxf(p0, p1));   // wave 0 = states 0..31
            if (threadIdx.x == 63) *lnm_s = (w > 0.f) ? __logf(w) : 0.f;
        }
        cur = nxt;
        lgkm_barrier();
    }
}

__global__ __launch_bounds__(256, 2)
void crf_half(const float* __restrict__ logits,    // [B, L, T]
              const int* __restrict__ tags,         // [B, L]
              const float* __restrict__ trans,      // [T, T]
              const float* __restrict__ start_t,    // [T]
              const float* __restrict__ end_t,      // [T]
              float* __restrict__ ws)               // av[B][T], bg[B][T], cf[B], cb[B], num[B]
{
    const int b    = blockIdx.x & (kB - 1);
    const int dir  = blockIdx.x >> 7;  // 0 = forward (steps 1..511 + bridge), 1 = backward (1022..512)
    const int tid  = threadIdx.x;      // 0..255
    const int pr   = tid >> 2;         // state pair 0..63 -> states 2pr, 2pr+1
    const int q    = tid & 3;          // k-quarter
    const int lane = tid & 63;
    const int wv   = tid >> 6;         // 0..3

    __shared__ __align__(16) float P[2][4 * kSec];   // padded scaled vector, dbuf
    __shared__ __align__(16) float em[2][kC * kT];   // exp(emission) chunks, 8KB
    __shared__ float lnm_s;
    __shared__ float red[4];

    const float* mylog = logits + (size_t)b * kL * kT;

    // ---------------- numerator (gold-path score), backward blocks ----------------
    float num = 0.f;
    if (dir == 1) {
        const int* mytags = tags + b * kL;
        float ns = 0.f;
        for (int p = tid; p < kL; p += 256) {
            const int tg = mytags[p];
            ns += mylog[(size_t)p * kT + tg];
            if (p < kL - 1) ns += trans[tg * kT + mytags[p + 1]];
        }
        if (tid == 0) ns += start_t[mytags[0]] + end_t[mytags[kL - 1]];
        #pragma unroll
        for (int off = 1; off < 64; off <<= 1) ns += __shfl_xor(ns, off);
        if (lane == 0) red[wv] = ns;
    }
    __syncthreads();
    if (dir == 1 && tid == 0) num = (red[0] + red[1]) + (red[2] + red[3]);

    // ---------------- E fragments in registers ----------------
    // forward: e0[t] = exp(trans[32q+t][2pr])   (output state = column)
    // backward: e0[t] = exp(trans[2pr][32q+t])  (output state = row)
    float e0[32], e1[32];
    if (dir == 0) {
        #pragma unroll
        for (int t = 0; t < 32; ++t) {
            const float2 tv = *(const float2*)(trans + (32 * q + t) * kT + 2 * pr);
            e0[t] = __expf(tv.x);
            e1[t] = __expf(tv.y);
        }
    } else {
        #pragma unroll
        for (int t4 = 0; t4 < 8; ++t4) {
            const float4 r0 = *(const float4*)(trans + (2 * pr)     * kT + 32 * q + 4 * t4);
            const float4 r1 = *(const float4*)(trans + (2 * pr + 1) * kT + 32 * q + 4 * t4);
            e0[4 * t4 + 0] = __expf(r0.x);  e0[4 * t4 + 1] = __expf(r0.y);
            e0[4 * t4 + 2] = __expf(r0.z);  e0[4 * t4 + 3] = __expf(r0.w);
            e1[4 * t4 + 0] = __expf(r1.x);  e1[4 * t4 + 1] = __expf(r1.y);
            e1[4 * t4 + 2] = __expf(r1.z);  e1[4 * t4 + 3] = __expf(r1.w);
        }
    }

    const int widx = kSec * (pr >> 4) + ((2 * pr) & 31);   // slot for state 2pr

    // ---------------- init vector ----------------
    // forward:  alpha_0 = exp(start + emit_0)
    // backward: bg_1023 = exp(end + emit_1023)
    {
        float v0, v1;
        if (dir == 0) {
            v0 = start_t[2 * pr]     + mylog[2 * pr];
            v1 = start_t[2 * pr + 1] + mylog[2 * pr + 1];
        } else {
            const size_t r = (size_t)(kL - 1) * kT;
            v0 = end_t[2 * pr]     + mylog[r + 2 * pr];
            v1 = end_t[2 * pr + 1] + mylog[r + 2 * pr + 1];
        }
        const float p0 = __expf(v0);
        const float p1 = __expf(v1);
        if (q == 0) *(float2*)(&P[0][widx]) = make_float2(p0, p1);
        if (wv == 0) {
            float w = fmaxf(p0, p1);
            #pragma unroll
            for (int off = 4; off < 64; off <<= 1) w = fmaxf(w, __shfl_xor(w, off));
            if (tid == 0) lnm_s = __logf(w);
        }
    }

    // ---------------- emission chunk staging ----------------
    // fwd: chunks ascend from row 1; bwd: chunk c holds ascending rows
    // 1007-16c..1022-16c, consumed in reverse via emstride=-kT from 15*kT.
    // Contiguous float4 layout: conflict-free ds_write_b128, coalesced global.
    const int base0 = (dir == 0) ? kT : 1007 * kT;
    const int cstep = (dir == 0) ? 16 * kT : -16 * kT;

    *(float4*)(&em[0][4 * tid])        = exp4(*(const float4*)(mylog + base0 + 4 * tid));
    *(float4*)(&em[0][1024 + 4 * tid]) = exp4(*(const float4*)(mylog + base0 + 1024 + 4 * tid));
    float4 g0 = *(const float4*)(mylog + base0 + cstep + 4 * tid);
    float4 g1 = *(const float4*)(mylog + base0 + cstep + 1024 + 4 * tid);
    lgkm_barrier();

    // ---------------- main recurrence: 511 steps (31 full chunks + 15) ----------------
    float C   = 0.f;
    int   cur = 0;
    const int emoff    = (dir == 0) ? 0 : 15 * kT;   // first-step row within chunk
    const int emstride = (dir == 0) ? kT : -kT;

    #pragma unroll 1
    for (int c = 0; c < 31; ++c) {
        // publish chunk c+1 (buffer (c+1)&1: consumed >=16 barriers later)
        *(float4*)(&em[(c + 1) & 1][4 * tid])        = exp4(g0);
        *(float4*)(&em[(c + 1) & 1][1024 + 4 * tid]) = exp4(g1);
        if (c <= 29) {   // preload chunk c+2 (rows in-bounds: fwd max 497, bwd min 511)
            const int base2 = base0 + (c + 2) * cstep;
            g0 = *(const float4*)(mylog + base2 + 4 * tid);
            g1 = *(const float4*)(mylog + base2 + 1024 + 4 * tid);
        }
        run_steps<kC>(em[c & 1] + emoff, emstride, pr, q, wv, e0, e1, widx, P, &lnm_s, C, cur);
    }
    // chunk 31: 15 steps (fwd rows 497..511 / bwd rows 526..512), already in em[1]
    run_steps<kC - 1>(em[1] + emoff, emstride, pr, q, wv, e0, e1, widx, P, &lnm_s, C, cur);

    // ---------------- epilogue ----------------
    float* ws_av = ws;                 // [kB][kT] scaled av = E^T alpha_511
    float* ws_bg = ws + kB * kT;       // [kB][kT] scaled bg_512
    float* ws_sc = ws + 2 * kB * kT;   // cf[kB], cb[kB], num[kB]

    if (dir == 0) {
        // bridge matvec: av[j] = sum_k alpha_511[k] * exp(trans[k][j])
        // (transition 511->512; no emission, no rescale)
        const float4* p4 = (const float4*)(P[cur] + kSec * q);
        float a00 = 0.f, a01 = 0.f, a02 = 0.f, a03 = 0.f;
        float a10 = 0.f, a11 = 0.f, a12 = 0.f, a13 = 0.f;
        #pragma unroll
        for (int t = 0; t < 8; ++t) {
            const float4 pv = p4[t];
            a00 = fmaf(pv.x, e0[4 * t + 0], a00);
            a01 = fmaf(pv.y, e0[4 * t + 1], a01);
            a02 = fmaf(pv.z, e0[4 * t + 2], a02);
            a03 = fmaf(pv.w, e0[4 * t + 3], a03);
            a10 = fmaf(pv.x, e1[4 * t + 0], a10);
            a11 = fmaf(pv.y, e1[4 * t + 1], a11);
            a12 = fmaf(pv.z, e1[4 * t + 2], a12);
            a13 = fmaf(pv.w, e1[4 * t + 3], a13);
        }
        float m0 = (a00 + a01) + (a02 + a03);
        float m1 = (a10 + a11) + (a12 + a13);
        m0 = quad_sum(m0);
        m1 = quad_sum(m1);
        if (q == 0) {
            ws_av[b * kT + 2 * pr]     = m0;
            ws_av[b * kT + 2 * pr + 1] = m1;
        }
        if (tid == 0) ws_sc[b] = C;
    } else {
        if (q == 0) {
            const float2 pv = *(const float2*)(&P[cur][widx]);
            ws_bg[b * kT + 2 * pr]     = pv.x;
            ws_bg[b * kT + 2 * pr + 1] = pv.y;
        }
        if (tid == 0) {
            ws_sc[kB + b]     = C;
            ws_sc[2 * kB + b] = num;
        }
    }
}

// Z_b = exp(cf+cb) * <av, bg>; out += sum_b (num_b - log Z_b)
__global__ void crf_combine(const float* __restrict__ ws, float* __restrict__ out)
{
    const int b = blockIdx.x;
    const int t = threadIdx.x;   // 0..63
    const float2 av = *(const float2*)(ws + b * kT + 2 * t);
    const float2 bg = *(const float2*)(ws + kB * kT + b * kT + 2 * t);
    float fp = av.x * bg.x + av.y * bg.y;
    #pragma unroll
    for (int off = 1; off < 64; off <<= 1) fp += __shfl_xor(fp, off);
    if (t == 0) {
        const float* sc = ws + 2 * kB * kT;
        const float logZ = sc[b] + sc[kB + b] + __logf(fp);
        atomicAdd(out, sc[2 * kB + b] - logZ);
    }
}

extern "C" void kernel_launch(void* const* d_in, const int* in_sizes, int n_in,
                              void* d_out, int out_size, void* d_ws, size_t ws_size,
                              hipStream_t stream) {
    const float* logits  = (const float*)d_in[0];
    const int*   tags    = (const int*)d_in[1];
    // d_in[2] = mask -- all true in this problem's setup, unused
    const float* trans   = (const float*)d_in[3];
    const float* start_t = (const float*)d_in[4];
    const float* end_t   = (const float*)d_in[5];
    float* out = (float*)d_out;
    float* ws  = (float*)d_ws;   // (2*128*128 + 3*128) floats = ~130 KB

    hipMemsetAsync(out, 0, sizeof(float), stream);
    crf_half<<<dim3(2 * kB), dim3(256), 0, stream>>>(logits, tags, trans, start_t, end_t, ws);
    crf_combine<<<dim3(kB), dim3(64), 0, stream>>>(ws, out);
}